// Round 5
// baseline (576.715 us; speedup 1.0000x reference)
//
#include <hip/hip_runtime.h>
#include <cstdint>
#include <cstddef>

// PointerNetwork: B=256, S=512, H=128, CHAR/CLASS=10, OUT=64, WE=32
// R4: fused MFMA recurrence, transposed orientation D = z^T.
//  - k_prep: blocks 0..255 row scan; block 256 XW1 f32 table; 257..352 pack
//            l1_Wh/l2_Wx/l2_Wh into f16 MFMA A-fragments (A = W^T).
//  - k_rec: 16 blocks x 512 thr; 16 rows/block lockstep. Wave w owns units
//           16w..16w+15 for all 4 gates (m-tiles g). B = h^T frags from LDS;
//           48 weight frags resident (192 regs, AGPR-legal as MFMA operands).
//           Gates per-lane (4 consecutive units, 1 row); XW1/bias added as f32.
//           2 barriers/step, double-buffered h1/h2 in LDS.
//  - k_out: subject GEMV + per-slot LN/po/sub folded + scatter (as R3).

#define SLOTCAP 128

typedef _Float16 half8 __attribute__((ext_vector_type(8)));
typedef float floatx4 __attribute__((ext_vector_type(4)));

union Frag { uint4 u; half8 h; };
union F4 { float4 v; float f[4]; };
union H4 { short4 s; _Float16 h[4]; };

__device__ __forceinline__ float fast_rcp(float x) {
#if __has_builtin(__builtin_amdgcn_rcpf)
    return __builtin_amdgcn_rcpf(x);
#else
    return 1.f / x;
#endif
}
__device__ __forceinline__ float sigm(float x) {
    return fast_rcp(1.f + __expf(-x));   // exp overflow->inf->rcp->0, safe
}
__device__ __forceinline__ float tanh_fast(float x) {
    x = fminf(fmaxf(x, -15.f), 15.f);
    float e = __expf(-2.f * x);
    return (1.f - e) * fast_rcp(1.f + e);
}
__device__ __forceinline__ void lstm_gate(float zi, float zf, float zg, float zo,
                                          bool act, float& c, float& h) {
    const float si = sigm(zi), sf = sigm(zf);
    const float tg = tanh_fast(zg), so = sigm(zo);
    const float cn = sf * c + si * tg;
    const float hn = so * tanh_fast(cn);
    if (act) { c = cn; h = hn; }
}

// ---------------- k_prep --------------------------------------------------
// blocks 0..255: per-row active scan -> idxbuf, wlist (tail zero), nactG
// block 256:     XW1[10][512] f32
// blocks 257..352: weight A-frags. A[m][k]: lane l holds m=l&15, k=8*(l>>4)+j.
//   frag r = w*16+g*4+kt: value = W[32kt+8lq+j][128g+16w+lm]
__global__ __launch_bounds__(256) void k_prep(
    const int* __restrict__ char_ids, const int* __restrict__ word_ids,
    const float* __restrict__ emb_char, const float* __restrict__ emb_word,
    const float* __restrict__ Wwc, const float* __restrict__ bwc,
    const float* __restrict__ l1_Wx, const float* __restrict__ l1_b,
    const float* __restrict__ l1_Wh, const float* __restrict__ l2_Wx,
    const float* __restrict__ l2_Wh,
    float* __restrict__ XW1, unsigned short* __restrict__ idxbuf,
    unsigned short* __restrict__ wlist, int* __restrict__ nactG,
    uint4* __restrict__ BW1, uint4* __restrict__ BWX, uint4* __restrict__ BWH)
{
    const int T = threadIdx.x;
    if (blockIdx.x < 256) {
        // ---- row scan ----
        __shared__ int charL[512];
        __shared__ int wordL[512];
        __shared__ short actT[512];
        __shared__ int ccnt[8];
        const int b = blockIdx.x;
        const int lane = T & 63;
        const int wv = T >> 6;
        charL[T] = char_ids[b * 512 + T];
        charL[256 + T] = char_ids[b * 512 + 256 + T];
        wordL[T] = word_ids[b * 512 + T];
        wordL[256 + T] = word_ids[b * 512 + 256 + T];
        __syncthreads();
        const bool a0 = (charL[T] == 0);
        const bool a1 = (charL[256 + T] == 0);
        const unsigned long long m0 = __ballot(a0);
        const unsigned long long m1 = __ballot(a1);
        if (lane == 0) { ccnt[wv] = (int)__popcll(m0); ccnt[4 + wv] = (int)__popcll(m1); }
        __syncthreads();
        int base0 = 0, base4 = 0, tot = 0;
        for (int i = 0; i < 8; ++i) {
            const int c = ccnt[i];
            if (i < wv) base0 += c;
            if (i < 4 + wv) base4 += c;
            tot += c;
        }
        const unsigned long long below = (1ull << lane) - 1ull;
        const unsigned long long upto  = (2ull << lane) - 1ull;
        if (a0) actT[base0 + (int)__popcll(m0 & below)] = (short)T;
        if (a1) actT[base4 + (int)__popcll(m1 & below)] = (short)(256 + T);
        {
            int c0 = base0 + (int)__popcll(m0 & upto);
            int c1 = base4 + (int)__popcll(m1 & upto);
            idxbuf[b * 512 + T] = (unsigned short)(c0 < SLOTCAP - 1 ? c0 : SLOTCAP - 1);
            idxbuf[b * 512 + 256 + T] = (unsigned short)(c1 < SLOTCAP - 1 ? c1 : SLOTCAP - 1);
        }
        __syncthreads();
        const int nclamp = (tot < SLOTCAP - 1) ? tot : SLOTCAP - 1;
        for (int a2 = T; a2 < SLOTCAP; a2 += 256)
            wlist[b * SLOTCAP + a2] =
                (a2 < nclamp) ? (unsigned short)wordL[actT[a2]] : (unsigned short)0;
        if (T == 0) nactG[b] = nclamp;
        return;
    }
    if (blockIdx.x == 256) {
        // ---- XW1 table (f32) ----
        __shared__ float xt[10][64];
        for (int i = T; i < 640; i += 256) {
            const int w = i >> 6, c = i & 63;
            float acc = emb_char[c] + bwc[c];
            for (int m = 0; m < 32; ++m) acc += emb_word[w * 32 + m] * Wwc[m * 64 + c];
            xt[w][c] = acc;
        }
        __syncthreads();
        for (int col = T; col < 512; col += 256) {
            const float bb = l1_b[col];
            for (int w = 0; w < 10; ++w) {
                float acc = bb;
                for (int k = 0; k < 64; ++k) acc += xt[w][k] * l1_Wx[k * 512 + col];
                XW1[w * 512 + col] = acc;
            }
        }
        return;
    }
    // ---- weight frag pack ----
    const int gid = (blockIdx.x - 257) * 256 + T;   // 0..24575
    const int fid = gid >> 6;                       // 0..383
    const int lane = gid & 63;
    const int m = fid >> 7;                         // 0=W1 1=WX 2=WH
    const int rsub = fid & 127;                     // = w*16+g*4+kt
    const int w = rsub >> 4, g = (rsub >> 2) & 3, kt = rsub & 3;
    const int lq = lane >> 4, lm = lane & 15;
    const int col = 128 * g + 16 * w + lm;
    const float* src = (m == 0) ? l1_Wh : (m == 1) ? l2_Wx : l2_Wh;
    uint4* dst = (m == 0) ? BW1 : (m == 1) ? BWX : BWH;
    Frag out;
    for (int j = 0; j < 8; ++j)
        out.h[j] = (_Float16)src[(32 * kt + 8 * lq + j) * 512 + col];
    dst[(size_t)rsub * 64 + lane] = out.u;
}

// ---------------- k_rec: fused 2-layer recurrence, 16 rows/block ------------
__global__ __launch_bounds__(512, 2) void k_rec(
    const uint4* __restrict__ BW1, const uint4* __restrict__ BWX,
    const uint4* __restrict__ BWH, const float* __restrict__ XW1,
    const float* __restrict__ l2_b, const unsigned short* __restrict__ wlist,
    const int* __restrict__ nactG, float* __restrict__ hbuf)
{
    const int r = blockIdx.x;       // rows 16r..16r+15
    const int T = threadIdx.x;
    const int w = T >> 6, l = T & 63;
    const int lq = l >> 4, lm = l & 15;
    const int u0 = 16 * w + 4 * lq;         // unit base (lane owns u0..u0+3)
    const size_t rowbase = (size_t)(16 * r);

    __shared__ _Float16 hA[2][16][136];     // h1 double buffer, [row][k]
    __shared__ _Float16 hB[2][16][136];     // h2 double buffer
    __shared__ unsigned short wt[16][130];
    __shared__ int nactS[16];
    __shared__ int nmax_s;

    // resident weight A-frags: 48 x uint4 = 192 regs (MFMA operands -> AGPR ok)
    Frag wf1[16], wfx[16], wfh[16];
    {
        const uint4* p1 = BW1 + (size_t)(w * 16) * 64 + l;
        const uint4* px = BWX + (size_t)(w * 16) * 64 + l;
        const uint4* ph = BWH + (size_t)(w * 16) * 64 + l;
#pragma unroll
        for (int i = 0; i < 16; ++i) {
            wf1[i].u = p1[i * 64];
            wfx[i].u = px[i * 64];
            wfh[i].u = ph[i * 64];
        }
    }
    F4 b2[4];
#pragma unroll
    for (int g = 0; g < 4; ++g) b2[g].v = *(const float4*)&l2_b[128 * g + u0];

    for (int i = T; i < 2176; i += 512) {
        ((_Float16*)hA[0])[i] = (_Float16)0.f;
        ((_Float16*)hB[0])[i] = (_Float16)0.f;
    }
    for (int i = T; i < 2048; i += 512) {
        wt[i >> 7][i & 127] = wlist[(rowbase + (i >> 7)) * SLOTCAP + (i & 127)];
        hbuf[((rowbase + (i >> 7)) * SLOTCAP) * 128 + (i & 127)] = 0.f;  // slot 0
    }
    if (T < 16) nactS[T] = nactG[16 * r + T];
    __syncthreads();
    if (T == 0) {
        int mx = 0;
        for (int m = 0; m < 16; ++m) mx = nactS[m] > mx ? nactS[m] : mx;
        nmax_s = mx;
    }
    __syncthreads();
    const int nmax = nmax_s;
    const int nact_l = nactS[lm];

    float c1[4] = {0.f,0.f,0.f,0.f}, c2[4] = {0.f,0.f,0.f,0.f};
    float h1v[4] = {0.f,0.f,0.f,0.f}, h2v[4] = {0.f,0.f,0.f,0.f};

    for (int a = 0; a < nmax; ++a) {
        const int cur = a & 1, nxt = cur ^ 1;
        const bool act = (a < nact_l);
        const int wd = (int)wt[lm][a];
        // x-contribution (f32, L2-hot), issued early
        F4 xw[4];
#pragma unroll
        for (int g = 0; g < 4; ++g)
            xw[g].v = *(const float4*)&XW1[wd * 512 + 128 * g + u0];

        // ---- layer 1: z1^T tiles ----
        Frag hb1[4];
#pragma unroll
        for (int kt = 0; kt < 4; ++kt)
            hb1[kt].u = *(const uint4*)&hA[cur][lm][32 * kt + 8 * lq];
        floatx4 acc[4];
#pragma unroll
        for (int g = 0; g < 4; ++g) {
            floatx4 z = {0.f, 0.f, 0.f, 0.f};
#pragma unroll
            for (int kt = 0; kt < 4; ++kt)
                z = __builtin_amdgcn_mfma_f32_16x16x32_f16(wf1[g * 4 + kt].h, hb1[kt].h, z, 0, 0, 0);
            acc[g] = z;
        }
#pragma unroll
        for (int rr = 0; rr < 4; ++rr)
            lstm_gate(acc[0][rr] + xw[0].f[rr], acc[1][rr] + xw[1].f[rr],
                      acc[2][rr] + xw[2].f[rr], acc[3][rr] + xw[3].f[rr],
                      act, c1[rr], h1v[rr]);
        {
            H4 hh;
#pragma unroll
            for (int rr = 0; rr < 4; ++rr) hh.h[rr] = (_Float16)h1v[rr];
            *(short4*)&hA[nxt][lm][u0] = hh.s;
        }
        // h2 frags (from cur buffer; writes go to nxt) — safe pre-barrier
        Frag hb2[4];
#pragma unroll
        for (int kt = 0; kt < 4; ++kt)
            hb2[kt].u = *(const uint4*)&hB[cur][lm][32 * kt + 8 * lq];
        __syncthreads();   // h1-new visible

        // ---- layer 2 ----
        Frag hbn[4];
#pragma unroll
        for (int kt = 0; kt < 4; ++kt)
            hbn[kt].u = *(const uint4*)&hA[nxt][lm][32 * kt + 8 * lq];
#pragma unroll
        for (int g = 0; g < 4; ++g) {
            floatx4 z = {b2[g].f[0], b2[g].f[1], b2[g].f[2], b2[g].f[3]};
#pragma unroll
            for (int kt = 0; kt < 4; ++kt)
                z = __builtin_amdgcn_mfma_f32_16x16x32_f16(wfh[g * 4 + kt].h, hb2[kt].h, z, 0, 0, 0);
#pragma unroll
            for (int kt = 0; kt < 4; ++kt)
                z = __builtin_amdgcn_mfma_f32_16x16x32_f16(wfx[g * 4 + kt].h, hbn[kt].h, z, 0, 0, 0);
            acc[g] = z;
        }
#pragma unroll
        for (int rr = 0; rr < 4; ++rr)
            lstm_gate(acc[0][rr], acc[1][rr], acc[2][rr], acc[3][rr],
                      act, c2[rr], h2v[rr]);
        {
            H4 hh;
#pragma unroll
            for (int rr = 0; rr < 4; ++rr) hh.h[rr] = (_Float16)h2v[rr];
            *(short4*)&hB[nxt][lm][u0] = hh.s;
        }
        if (act) {
            float4 hv; hv.x = h2v[0]; hv.y = h2v[1]; hv.z = h2v[2]; hv.w = h2v[3];
            *(float4*)&hbuf[((rowbase + lm) * SLOTCAP + (a + 1)) * 128 + u0] = hv;
        }
        __syncthreads();   // h2-new visible / buffer rotate
    }
}

// ---------------- k_out: subject GEMV + per-slot LN/po/sub + scatter --------
__global__ __launch_bounds__(256) void k_out(
    const int* __restrict__ subject_ids,
    const unsigned short* __restrict__ idxbuf, const float* __restrict__ hbuf,
    const float* __restrict__ beta_W, const float* __restrict__ beta_b,
    const float* __restrict__ gamma_W, const float* __restrict__ gamma_b,
    const float* __restrict__ sub_W, const float* __restrict__ sub_b,
    const float* __restrict__ po_W, const float* __restrict__ po_b,
    float* __restrict__ out)
{
    const int b = blockIdx.x;
    const int T = threadIdx.x;   // 0..255
    __shared__ float A[20][132];          // A[o][c] = gm[c]*po_W[c*20+o]
    __shared__ float K1[20], K2[20];
    __shared__ float gm[128], bt[128];
    __shared__ float subj[256];
    __shared__ float urs[SLOTCAP][2];
    __shared__ float povals[SLOTCAP * 20];
    __shared__ float subv[SLOTCAP * 2];
    __shared__ unsigned short idxr[512];
    __shared__ float swl[256];

    idxr[T] = idxbuf[b * 512 + T];
    idxr[256 + T] = idxbuf[b * 512 + 256 + T];
    swl[T] = sub_W[T];
    {
        const int s0 = subject_ids[b * 2 + 0];
        const int s1 = subject_ids[b * 2 + 1];
        const int i0 = idxbuf[b * 512 + s0];
        const int i1 = idxbuf[b * 512 + s1];
        if (T < 128) subj[T] = hbuf[((size_t)b * SLOTCAP + i0) * 128 + T];
        else         subj[T] = hbuf[((size_t)b * SLOTCAP + i1) * 128 + (T - 128)];
    }
    __syncthreads();

    {   // beta (T<128) / gamma (T>=128) GEMV
        const int uu = T & 127;
        const float* Wm = (T < 128) ? beta_W : gamma_W;
        float acc = (T < 128) ? beta_b[uu] : gamma_b[uu];
        for (int c = 0; c < 256; ++c) acc += subj[c] * Wm[c * 128 + uu];
        if (T < 128) bt[uu] = acc; else gm[uu] = acc;
    }
    __syncthreads();

    for (int i = T; i < 2560; i += 256) {
        const int o = i >> 7, c = i & 127;
        A[o][c] = gm[c] * po_W[c * 20 + o];
    }
    if (T < 20) {
        float k1 = po_b[T], k2 = 0.f;
        for (int c = 0; c < 128; ++c) {
            const float pw = po_W[c * 20 + T];
            k1 += bt[c] * pw;
            k2 += gm[c] * pw;
        }
        K1[T] = k1; K2[T] = k2;
    }
    const int nslot = (int)idxr[511] + 1;
    const float sb0 = sub_b[0], sb1 = sub_b[1];
    for (int s = T; s < nslot; s += 256) {
        const float4* hp4 = (const float4*)(hbuf + ((size_t)b * SLOTCAP + s) * 128);
        float sum = 0.f, s2 = 0.f, sub0 = sb0, sub1 = sb1;
        for (int c4 = 0; c4 < 32; ++c4) {
            const float4 h = hp4[c4];
            sum += (h.x + h.y) + (h.z + h.w);
            s2  += h.x * h.x + h.y * h.y + h.z * h.z + h.w * h.w;
            const int c = 4 * c4;
            sub0 += h.x * swl[2 * c] + h.y * swl[2 * c + 2] + h.z * swl[2 * c + 4] + h.w * swl[2 * c + 6];
            sub1 += h.x * swl[2 * c + 1] + h.y * swl[2 * c + 3] + h.z * swl[2 * c + 5] + h.w * swl[2 * c + 7];
        }
        const float uu = sum * (1.f / 128.f);
        const float v = fmaxf(s2 * (1.f / 128.f) - uu * uu, 0.f);
        urs[s][0] = uu;
        urs[s][1] = 1.f / sqrtf(v + 1e-12f);
        subv[2 * s] = sub0; subv[2 * s + 1] = sub1;
    }
    __syncthreads();

    for (int i = T; i < nslot * 20; i += 256) {
        const int s = i / 20, o = i - 20 * s;
        const float uu = urs[s][0], rs = urs[s][1];
        const float4* hp4 = (const float4*)(hbuf + ((size_t)b * SLOTCAP + s) * 128);
        const float* Ao = &A[o][0];
        float acc = 0.f;
        for (int c4 = 0; c4 < 32; ++c4) {
            const float4 h = hp4[c4];
            const float4 aa = *(const float4*)&Ao[4 * c4];
            acc += h.x * aa.x + h.y * aa.y + h.z * aa.z + h.w * aa.w;
        }
        povals[i] = rs * acc - uu * rs * K2[o] + K1[o];
    }
    __syncthreads();

    for (int i = T; i < 2560; i += 256) {
        const int t = i / 5, j = i - 5 * t;
        const int sl = idxr[t];
        const float4 v = *(const float4*)&povals[sl * 20 + 4 * j];
        *(float4*)&out[262144 + ((size_t)(b * 512 + t)) * 20 + 4 * j] = v;
    }
    for (int i = T; i < 512; i += 256) {
        const int sl = idxr[i];
        float2 v; v.x = subv[2 * sl]; v.y = subv[2 * sl + 1];
        *(float2*)&out[((size_t)(b * 512 + i)) * 2] = v;
    }
}

extern "C" void kernel_launch(void* const* d_in, const int* in_sizes, int n_in,
                              void* d_out, int out_size, void* d_ws, size_t ws_size,
                              hipStream_t stream) {
    (void)in_sizes; (void)n_in; (void)out_size; (void)ws_size;
    const int*   char_ids    = (const int*)d_in[0];
    const int*   word_ids    = (const int*)d_in[1];
    const int*   subject_ids = (const int*)d_in[2];
    const float* emb_char    = (const float*)d_in[3];
    const float* emb_word    = (const float*)d_in[4];
    const float* Wwc         = (const float*)d_in[5];
    const float* bwc         = (const float*)d_in[6];
    const float* l1_Wx       = (const float*)d_in[7];
    const float* l1_Wh       = (const float*)d_in[8];
    const float* l1_b        = (const float*)d_in[9];
    const float* l2_Wx       = (const float*)d_in[10];
    const float* l2_Wh       = (const float*)d_in[11];
    const float* l2_b        = (const float*)d_in[12];
    const float* beta_W      = (const float*)d_in[13];
    const float* beta_b      = (const float*)d_in[14];
    const float* gamma_W     = (const float*)d_in[15];
    const float* gamma_b     = (const float*)d_in[16];
    const float* sub_W       = (const float*)d_in[17];
    const float* sub_b       = (const float*)d_in[18];
    const float* po_W        = (const float*)d_in[19];
    const float* po_b        = (const float*)d_in[20];
    float* out = (float*)d_out;

    char* ws = (char*)d_ws;
    float*          XW1    = (float*)(ws + 0);                // 20480 B (pad 32768)
    uint4*          BW1    = (uint4*)(ws + 32768);            // 131072 B
    uint4*          BWX    = (uint4*)(ws + 163840);           // 131072 B
    uint4*          BWH    = (uint4*)(ws + 294912);           // 131072 B
    unsigned short* idxbuf = (unsigned short*)(ws + 425984);  // 262144 B
    unsigned short* wlist  = (unsigned short*)(ws + 688128);  // 65536 B
    int*            nactG  = (int*)(ws + 753664);             // 1024 B
    float*          hbuf   = (float*)(ws + 786432);           // 16777216 B

    k_prep<<<dim3(353), dim3(256), 0, stream>>>(char_ids, word_ids, emb_char, emb_word,
                                                Wwc, bwc, l1_Wx, l1_b, l1_Wh, l2_Wx, l2_Wh,
                                                XW1, idxbuf, wlist, nactG, BW1, BWX, BWH);
    k_rec<<<dim3(16), dim3(512), 0, stream>>>(BW1, BWX, BWH, XW1, l2_b, wlist, nactG, hbuf);
    k_out<<<dim3(256), dim3(256), 0, stream>>>(subject_ids, idxbuf, hbuf,
                                               beta_W, beta_b, gamma_W, gamma_b,
                                               sub_W, sub_b, po_W, po_b, out);
}

// Round 6
// 575.516 us; speedup vs baseline: 1.0021x; 1.0021x over previous
//
#include <hip/hip_runtime.h>
#include <cstdint>
#include <cstddef>

// PointerNetwork: B=256, S=512, H=128, CHAR/CLASS=10, OUT=64, WE=32
// R5 = R4 with the launch-bounds fix on k_rec:
//   __launch_bounds__(512,2) forced 4 waves/SIMD -> 128 unified regs/wave ->
//   the 48 weight frags (192 regs) were compiler-spilled to scratch and
//   reloaded every step (L2-hit scratch: invisible in FETCH_SIZE, ~8k cyc/step).
//   Plain __launch_bounds__(512) allows ~240+ regs/wave (2 waves/SIMD) and
//   keeps the frags resident (R3-verified behavior).
//  - k_prep: blocks 0..255 row scan; block 256 XW1 f32 table; 257..352 pack
//            l1_Wh/l2_Wx/l2_Wh into f16 MFMA A-fragments (A = W^T).
//  - k_rec: 16 blocks x 512 thr; 16 rows/block lockstep; D = z^T orientation;
//           gates per-lane; f32 XW1/bias; 2 barriers/step; LDS dbuf h1/h2.
//  - k_out: subject GEMV + per-slot LN/po/sub folded + scatter.

#define SLOTCAP 128

typedef _Float16 half8 __attribute__((ext_vector_type(8)));
typedef float floatx4 __attribute__((ext_vector_type(4)));

union Frag { uint4 u; half8 h; };
union F4 { float4 v; float f[4]; };
union H4 { short4 s; _Float16 h[4]; };

__device__ __forceinline__ float fast_rcp(float x) {
#if __has_builtin(__builtin_amdgcn_rcpf)
    return __builtin_amdgcn_rcpf(x);
#else
    return 1.f / x;
#endif
}
__device__ __forceinline__ float sigm(float x) {
    return fast_rcp(1.f + __expf(-x));   // exp overflow->inf->rcp->0, safe
}
__device__ __forceinline__ float tanh_fast(float x) {
    x = fminf(fmaxf(x, -15.f), 15.f);
    float e = __expf(-2.f * x);
    return (1.f - e) * fast_rcp(1.f + e);
}
__device__ __forceinline__ void lstm_gate(float zi, float zf, float zg, float zo,
                                          bool act, float& c, float& h) {
    const float si = sigm(zi), sf = sigm(zf);
    const float tg = tanh_fast(zg), so = sigm(zo);
    const float cn = sf * c + si * tg;
    const float hn = so * tanh_fast(cn);
    if (act) { c = cn; h = hn; }
}

// ---------------- k_prep --------------------------------------------------
// blocks 0..255: per-row active scan -> idxbuf, wlist (tail zero), nactG
// block 256:     XW1[10][512] f32
// blocks 257..352: weight A-frags. A[m][k]: lane l holds m=l&15, k=8*(l>>4)+j.
//   frag r = w*16+g*4+kt: value = W[32kt+8lq+j][128g+16w+lm]
__global__ __launch_bounds__(256) void k_prep(
    const int* __restrict__ char_ids, const int* __restrict__ word_ids,
    const float* __restrict__ emb_char, const float* __restrict__ emb_word,
    const float* __restrict__ Wwc, const float* __restrict__ bwc,
    const float* __restrict__ l1_Wx, const float* __restrict__ l1_b,
    const float* __restrict__ l1_Wh, const float* __restrict__ l2_Wx,
    const float* __restrict__ l2_Wh,
    float* __restrict__ XW1, unsigned short* __restrict__ idxbuf,
    unsigned short* __restrict__ wlist, int* __restrict__ nactG,
    uint4* __restrict__ BW1, uint4* __restrict__ BWX, uint4* __restrict__ BWH)
{
    const int T = threadIdx.x;
    if (blockIdx.x < 256) {
        // ---- row scan ----
        __shared__ int charL[512];
        __shared__ int wordL[512];
        __shared__ short actT[512];
        __shared__ int ccnt[8];
        const int b = blockIdx.x;
        const int lane = T & 63;
        const int wv = T >> 6;
        charL[T] = char_ids[b * 512 + T];
        charL[256 + T] = char_ids[b * 512 + 256 + T];
        wordL[T] = word_ids[b * 512 + T];
        wordL[256 + T] = word_ids[b * 512 + 256 + T];
        __syncthreads();
        const bool a0 = (charL[T] == 0);
        const bool a1 = (charL[256 + T] == 0);
        const unsigned long long m0 = __ballot(a0);
        const unsigned long long m1 = __ballot(a1);
        if (lane == 0) { ccnt[wv] = (int)__popcll(m0); ccnt[4 + wv] = (int)__popcll(m1); }
        __syncthreads();
        int base0 = 0, base4 = 0, tot = 0;
        for (int i = 0; i < 8; ++i) {
            const int c = ccnt[i];
            if (i < wv) base0 += c;
            if (i < 4 + wv) base4 += c;
            tot += c;
        }
        const unsigned long long below = (1ull << lane) - 1ull;
        const unsigned long long upto  = (2ull << lane) - 1ull;
        if (a0) actT[base0 + (int)__popcll(m0 & below)] = (short)T;
        if (a1) actT[base4 + (int)__popcll(m1 & below)] = (short)(256 + T);
        {
            int c0 = base0 + (int)__popcll(m0 & upto);
            int c1 = base4 + (int)__popcll(m1 & upto);
            idxbuf[b * 512 + T] = (unsigned short)(c0 < SLOTCAP - 1 ? c0 : SLOTCAP - 1);
            idxbuf[b * 512 + 256 + T] = (unsigned short)(c1 < SLOTCAP - 1 ? c1 : SLOTCAP - 1);
        }
        __syncthreads();
        const int nclamp = (tot < SLOTCAP - 1) ? tot : SLOTCAP - 1;
        for (int a2 = T; a2 < SLOTCAP; a2 += 256)
            wlist[b * SLOTCAP + a2] =
                (a2 < nclamp) ? (unsigned short)wordL[actT[a2]] : (unsigned short)0;
        if (T == 0) nactG[b] = nclamp;
        return;
    }
    if (blockIdx.x == 256) {
        // ---- XW1 table (f32) ----
        __shared__ float xt[10][64];
        for (int i = T; i < 640; i += 256) {
            const int w = i >> 6, c = i & 63;
            float acc = emb_char[c] + bwc[c];
            for (int m = 0; m < 32; ++m) acc += emb_word[w * 32 + m] * Wwc[m * 64 + c];
            xt[w][c] = acc;
        }
        __syncthreads();
        for (int col = T; col < 512; col += 256) {
            const float bb = l1_b[col];
            for (int w = 0; w < 10; ++w) {
                float acc = bb;
                for (int k = 0; k < 64; ++k) acc += xt[w][k] * l1_Wx[k * 512 + col];
                XW1[w * 512 + col] = acc;
            }
        }
        return;
    }
    // ---- weight frag pack ----
    const int gid = (blockIdx.x - 257) * 256 + T;   // 0..24575
    const int fid = gid >> 6;                       // 0..383
    const int lane = gid & 63;
    const int m = fid >> 7;                         // 0=W1 1=WX 2=WH
    const int rsub = fid & 127;                     // = w*16+g*4+kt
    const int w = rsub >> 4, g = (rsub >> 2) & 3, kt = rsub & 3;
    const int lq = lane >> 4, lm = lane & 15;
    const int col = 128 * g + 16 * w + lm;
    const float* src = (m == 0) ? l1_Wh : (m == 1) ? l2_Wx : l2_Wh;
    uint4* dst = (m == 0) ? BW1 : (m == 1) ? BWX : BWH;
    Frag out;
    for (int j = 0; j < 8; ++j)
        out.h[j] = (_Float16)src[(32 * kt + 8 * lq + j) * 512 + col];
    dst[(size_t)rsub * 64 + lane] = out.u;
}

// ---------------- k_rec: fused 2-layer recurrence, 16 rows/block ------------
// NOTE: no min-waves in launch_bounds — 192 frag regs/thread must stay
// resident; (512,2) caps unified regs at 128/wave and forces scratch spill.
__global__ __launch_bounds__(512) void k_rec(
    const uint4* __restrict__ BW1, const uint4* __restrict__ BWX,
    const uint4* __restrict__ BWH, const float* __restrict__ XW1,
    const float* __restrict__ l2_b, const unsigned short* __restrict__ wlist,
    const int* __restrict__ nactG, float* __restrict__ hbuf)
{
    const int r = blockIdx.x;       // rows 16r..16r+15
    const int T = threadIdx.x;
    const int w = T >> 6, l = T & 63;
    const int lq = l >> 4, lm = l & 15;
    const int u0 = 16 * w + 4 * lq;         // unit base (lane owns u0..u0+3)
    const size_t rowbase = (size_t)(16 * r);

    __shared__ _Float16 hA[2][16][136];     // h1 double buffer, [row][k]
    __shared__ _Float16 hB[2][16][136];     // h2 double buffer
    __shared__ unsigned short wt[16][130];
    __shared__ int nactS[16];
    __shared__ int nmax_s;

    // resident weight A-frags: 48 x uint4 = 192 regs (MFMA operands -> AGPR ok)
    Frag wf1[16], wfx[16], wfh[16];
    {
        const uint4* p1 = BW1 + (size_t)(w * 16) * 64 + l;
        const uint4* px = BWX + (size_t)(w * 16) * 64 + l;
        const uint4* ph = BWH + (size_t)(w * 16) * 64 + l;
#pragma unroll
        for (int i = 0; i < 16; ++i) {
            wf1[i].u = p1[i * 64];
            wfx[i].u = px[i * 64];
            wfh[i].u = ph[i * 64];
        }
    }
    F4 b2[4];
#pragma unroll
    for (int g = 0; g < 4; ++g) b2[g].v = *(const float4*)&l2_b[128 * g + u0];

    for (int i = T; i < 2176; i += 512) {
        ((_Float16*)hA[0])[i] = (_Float16)0.f;
        ((_Float16*)hB[0])[i] = (_Float16)0.f;
    }
    for (int i = T; i < 2048; i += 512) {
        wt[i >> 7][i & 127] = wlist[(rowbase + (i >> 7)) * SLOTCAP + (i & 127)];
        hbuf[((rowbase + (i >> 7)) * SLOTCAP) * 128 + (i & 127)] = 0.f;  // slot 0
    }
    if (T < 16) nactS[T] = nactG[16 * r + T];
    __syncthreads();
    if (T == 0) {
        int mx = 0;
        for (int m = 0; m < 16; ++m) mx = nactS[m] > mx ? nactS[m] : mx;
        nmax_s = mx;
    }
    __syncthreads();
    const int nmax = nmax_s;
    const int nact_l = nactS[lm];

    float c1[4] = {0.f,0.f,0.f,0.f}, c2[4] = {0.f,0.f,0.f,0.f};
    float h1v[4] = {0.f,0.f,0.f,0.f}, h2v[4] = {0.f,0.f,0.f,0.f};

    for (int a = 0; a < nmax; ++a) {
        const int cur = a & 1, nxt = cur ^ 1;
        const bool act = (a < nact_l);
        const int wd = (int)wt[lm][a];
        // x-contribution (f32, L2-hot), issued early
        F4 xw[4];
#pragma unroll
        for (int g = 0; g < 4; ++g)
            xw[g].v = *(const float4*)&XW1[wd * 512 + 128 * g + u0];

        // ---- layer 1: z1^T tiles ----
        Frag hb1[4];
#pragma unroll
        for (int kt = 0; kt < 4; ++kt)
            hb1[kt].u = *(const uint4*)&hA[cur][lm][32 * kt + 8 * lq];
        floatx4 acc[4];
#pragma unroll
        for (int g = 0; g < 4; ++g) {
            floatx4 z = {0.f, 0.f, 0.f, 0.f};
#pragma unroll
            for (int kt = 0; kt < 4; ++kt)
                z = __builtin_amdgcn_mfma_f32_16x16x32_f16(wf1[g * 4 + kt].h, hb1[kt].h, z, 0, 0, 0);
            acc[g] = z;
        }
#pragma unroll
        for (int rr = 0; rr < 4; ++rr)
            lstm_gate(acc[0][rr] + xw[0].f[rr], acc[1][rr] + xw[1].f[rr],
                      acc[2][rr] + xw[2].f[rr], acc[3][rr] + xw[3].f[rr],
                      act, c1[rr], h1v[rr]);
        {
            H4 hh;
#pragma unroll
            for (int rr = 0; rr < 4; ++rr) hh.h[rr] = (_Float16)h1v[rr];
            *(short4*)&hA[nxt][lm][u0] = hh.s;
        }
        // h2 frags (from cur buffer; writes go to nxt) — safe pre-barrier
        Frag hb2[4];
#pragma unroll
        for (int kt = 0; kt < 4; ++kt)
            hb2[kt].u = *(const uint4*)&hB[cur][lm][32 * kt + 8 * lq];
        __syncthreads();   // h1-new visible

        // ---- layer 2 ----
        Frag hbn[4];
#pragma unroll
        for (int kt = 0; kt < 4; ++kt)
            hbn[kt].u = *(const uint4*)&hA[nxt][lm][32 * kt + 8 * lq];
#pragma unroll
        for (int g = 0; g < 4; ++g) {
            floatx4 z = {b2[g].f[0], b2[g].f[1], b2[g].f[2], b2[g].f[3]};
#pragma unroll
            for (int kt = 0; kt < 4; ++kt)
                z = __builtin_amdgcn_mfma_f32_16x16x32_f16(wfh[g * 4 + kt].h, hb2[kt].h, z, 0, 0, 0);
#pragma unroll
            for (int kt = 0; kt < 4; ++kt)
                z = __builtin_amdgcn_mfma_f32_16x16x32_f16(wfx[g * 4 + kt].h, hbn[kt].h, z, 0, 0, 0);
            acc[g] = z;
        }
#pragma unroll
        for (int rr = 0; rr < 4; ++rr)
            lstm_gate(acc[0][rr], acc[1][rr], acc[2][rr], acc[3][rr],
                      act, c2[rr], h2v[rr]);
        {
            H4 hh;
#pragma unroll
            for (int rr = 0; rr < 4; ++rr) hh.h[rr] = (_Float16)h2v[rr];
            *(short4*)&hB[nxt][lm][u0] = hh.s;
        }
        if (act) {
            float4 hv; hv.x = h2v[0]; hv.y = h2v[1]; hv.z = h2v[2]; hv.w = h2v[3];
            *(float4*)&hbuf[((rowbase + lm) * SLOTCAP + (a + 1)) * 128 + u0] = hv;
        }
        __syncthreads();   // h2-new visible / buffer rotate
    }
}

// ---------------- k_out: subject GEMV + per-slot LN/po/sub + scatter --------
__global__ __launch_bounds__(256) void k_out(
    const int* __restrict__ subject_ids,
    const unsigned short* __restrict__ idxbuf, const float* __restrict__ hbuf,
    const float* __restrict__ beta_W, const float* __restrict__ beta_b,
    const float* __restrict__ gamma_W, const float* __restrict__ gamma_b,
    const float* __restrict__ sub_W, const float* __restrict__ sub_b,
    const float* __restrict__ po_W, const float* __restrict__ po_b,
    float* __restrict__ out)
{
    const int b = blockIdx.x;
    const int T = threadIdx.x;   // 0..255
    __shared__ float A[20][132];          // A[o][c] = gm[c]*po_W[c*20+o]
    __shared__ float K1[20], K2[20];
    __shared__ float gm[128], bt[128];
    __shared__ float subj[256];
    __shared__ float urs[SLOTCAP][2];
    __shared__ float povals[SLOTCAP * 20];
    __shared__ float subv[SLOTCAP * 2];
    __shared__ unsigned short idxr[512];
    __shared__ float swl[256];

    idxr[T] = idxbuf[b * 512 + T];
    idxr[256 + T] = idxbuf[b * 512 + 256 + T];
    swl[T] = sub_W[T];
    {
        const int s0 = subject_ids[b * 2 + 0];
        const int s1 = subject_ids[b * 2 + 1];
        const int i0 = idxbuf[b * 512 + s0];
        const int i1 = idxbuf[b * 512 + s1];
        if (T < 128) subj[T] = hbuf[((size_t)b * SLOTCAP + i0) * 128 + T];
        else         subj[T] = hbuf[((size_t)b * SLOTCAP + i1) * 128 + (T - 128)];
    }
    __syncthreads();

    {   // beta (T<128) / gamma (T>=128) GEMV
        const int uu = T & 127;
        const float* Wm = (T < 128) ? beta_W : gamma_W;
        float acc = (T < 128) ? beta_b[uu] : gamma_b[uu];
        for (int c = 0; c < 256; ++c) acc += subj[c] * Wm[c * 128 + uu];
        if (T < 128) bt[uu] = acc; else gm[uu] = acc;
    }
    __syncthreads();

    for (int i = T; i < 2560; i += 256) {
        const int o = i >> 7, c = i & 127;
        A[o][c] = gm[c] * po_W[c * 20 + o];
    }
    if (T < 20) {
        float k1 = po_b[T], k2 = 0.f;
        for (int c = 0; c < 128; ++c) {
            const float pw = po_W[c * 20 + T];
            k1 += bt[c] * pw;
            k2 += gm[c] * pw;
        }
        K1[T] = k1; K2[T] = k2;
    }
    const int nslot = (int)idxr[511] + 1;
    const float sb0 = sub_b[0], sb1 = sub_b[1];
    for (int s = T; s < nslot; s += 256) {
        const float4* hp4 = (const float4*)(hbuf + ((size_t)b * SLOTCAP + s) * 128);
        float sum = 0.f, s2 = 0.f, sub0 = sb0, sub1 = sb1;
        for (int c4 = 0; c4 < 32; ++c4) {
            const float4 h = hp4[c4];
            sum += (h.x + h.y) + (h.z + h.w);
            s2  += h.x * h.x + h.y * h.y + h.z * h.z + h.w * h.w;
            const int c = 4 * c4;
            sub0 += h.x * swl[2 * c] + h.y * swl[2 * c + 2] + h.z * swl[2 * c + 4] + h.w * swl[2 * c + 6];
            sub1 += h.x * swl[2 * c + 1] + h.y * swl[2 * c + 3] + h.z * swl[2 * c + 5] + h.w * swl[2 * c + 7];
        }
        const float uu = sum * (1.f / 128.f);
        const float v = fmaxf(s2 * (1.f / 128.f) - uu * uu, 0.f);
        urs[s][0] = uu;
        urs[s][1] = 1.f / sqrtf(v + 1e-12f);
        subv[2 * s] = sub0; subv[2 * s + 1] = sub1;
    }
    __syncthreads();

    for (int i = T; i < nslot * 20; i += 256) {
        const int s = i / 20, o = i - 20 * s;
        const float uu = urs[s][0], rs = urs[s][1];
        const float4* hp4 = (const float4*)(hbuf + ((size_t)b * SLOTCAP + s) * 128);
        const float* Ao = &A[o][0];
        float acc = 0.f;
        for (int c4 = 0; c4 < 32; ++c4) {
            const float4 h = hp4[c4];
            const float4 aa = *(const float4*)&Ao[4 * c4];
            acc += h.x * aa.x + h.y * aa.y + h.z * aa.z + h.w * aa.w;
        }
        povals[i] = rs * acc - uu * rs * K2[o] + K1[o];
    }
    __syncthreads();

    for (int i = T; i < 2560; i += 256) {
        const int t = i / 5, j = i - 5 * t;
        const int sl = idxr[t];
        const float4 v = *(const float4*)&povals[sl * 20 + 4 * j];
        *(float4*)&out[262144 + ((size_t)(b * 512 + t)) * 20 + 4 * j] = v;
    }
    for (int i = T; i < 512; i += 256) {
        const int sl = idxr[i];
        float2 v; v.x = subv[2 * sl]; v.y = subv[2 * sl + 1];
        *(float2*)&out[((size_t)(b * 512 + i)) * 2] = v;
    }
}

extern "C" void kernel_launch(void* const* d_in, const int* in_sizes, int n_in,
                              void* d_out, int out_size, void* d_ws, size_t ws_size,
                              hipStream_t stream) {
    (void)in_sizes; (void)n_in; (void)out_size; (void)ws_size;
    const int*   char_ids    = (const int*)d_in[0];
    const int*   word_ids    = (const int*)d_in[1];
    const int*   subject_ids = (const int*)d_in[2];
    const float* emb_char    = (const float*)d_in[3];
    const float* emb_word    = (const float*)d_in[4];
    const float* Wwc         = (const float*)d_in[5];
    const float* bwc         = (const float*)d_in[6];
    const float* l1_Wx       = (const float*)d_in[7];
    const float* l1_Wh       = (const float*)d_in[8];
    const float* l1_b        = (const float*)d_in[9];
    const float* l2_Wx       = (const float*)d_in[10];
    const float* l2_Wh       = (const float*)d_in[11];
    const float* l2_b        = (const float*)d_in[12];
    const float* beta_W      = (const float*)d_in[13];
    const float* beta_b      = (const float*)d_in[14];
    const float* gamma_W     = (const float*)d_in[15];
    const float* gamma_b     = (const float*)d_in[16];
    const float* sub_W       = (const float*)d_in[17];
    const float* sub_b       = (const float*)d_in[18];
    const float* po_W        = (const float*)d_in[19];
    const float* po_b        = (const float*)d_in[20];
    float* out = (float*)d_out;

    char* ws = (char*)d_ws;
    float*          XW1    = (float*)(ws + 0);                // 20480 B (pad 32768)
    uint4*          BW1    = (uint4*)(ws + 32768);            // 131072 B
    uint4*          BWX    = (uint4*)(ws + 163840);           // 131072 B
    uint4*          BWH    = (uint4*)(ws + 294912);           // 131072 B
    unsigned short* idxbuf = (unsigned short*)(ws + 425984);  // 262144 B
    unsigned short* wlist  = (unsigned short*)(ws + 688128);  // 65536 B
    int*            nactG  = (int*)(ws + 753664);             // 1024 B
    float*          hbuf   = (float*)(ws + 786432);           // 16777216 B

    k_prep<<<dim3(353), dim3(256), 0, stream>>>(char_ids, word_ids, emb_char, emb_word,
                                                Wwc, bwc, l1_Wx, l1_b, l1_Wh, l2_Wx, l2_Wh,
                                                XW1, idxbuf, wlist, nactG, BW1, BWX, BWH);
    k_rec<<<dim3(16), dim3(512), 0, stream>>>(BW1, BWX, BWH, XW1, l2_b, wlist, nactG, hbuf);
    k_out<<<dim3(256), dim3(256), 0, stream>>>(subject_ids, idxbuf, hbuf,
                                               beta_W, beta_b, gamma_W, gamma_b,
                                               sub_W, sub_b, po_W, po_b, out);
}

// Round 7
// 488.075 us; speedup vs baseline: 1.1816x; 1.1792x over previous
//
#include <hip/hip_runtime.h>
#include <cstdint>
#include <cstddef>

// PointerNetwork: B=256, S=512, H=128, CHAR/CLASS=10, OUT=64, WE=32
// R6 = R5 + occupancy cap on k_rec:
//   R4/R5 evidence: scheduler targets 4 waves/EU (128 unified regs/wave) by
//   default and spills the 192-reg weight frags to scratch no matter what
//   __launch_bounds__ allows. amdgpu_waves_per_eu(2,2) pins occupancy at
//   2 waves/EU -> 256 unified regs/wave -> frags resident.
//   Also: XW1 table back to 10 blocks (was 1 block = 1 CU serial tail).
//  - k_prep: blocks 0..255 row scan; 256..265 XW1 (w per block); 266..361 pack
//            l1_Wh/l2_Wx/l2_Wh into f16 MFMA A-fragments (A = W^T).
//  - k_rec: 16 blocks x 512 thr; 16 rows/block lockstep; D = z^T orientation;
//           gates per-lane; f32 XW1/bias; 2 barriers/step; LDS dbuf h1/h2.
//  - k_out: subject GEMV + per-slot LN/po/sub folded + scatter.

#define SLOTCAP 128

typedef _Float16 half8 __attribute__((ext_vector_type(8)));
typedef float floatx4 __attribute__((ext_vector_type(4)));

union Frag { uint4 u; half8 h; };
union F4 { float4 v; float f[4]; };
union H4 { short4 s; _Float16 h[4]; };

__device__ __forceinline__ float fast_rcp(float x) {
#if __has_builtin(__builtin_amdgcn_rcpf)
    return __builtin_amdgcn_rcpf(x);
#else
    return 1.f / x;
#endif
}
__device__ __forceinline__ float sigm(float x) {
    return fast_rcp(1.f + __expf(-x));   // exp overflow->inf->rcp->0, safe
}
__device__ __forceinline__ float tanh_fast(float x) {
    x = fminf(fmaxf(x, -15.f), 15.f);
    float e = __expf(-2.f * x);
    return (1.f - e) * fast_rcp(1.f + e);
}
__device__ __forceinline__ void lstm_gate(float zi, float zf, float zg, float zo,
                                          bool act, float& c, float& h) {
    const float si = sigm(zi), sf = sigm(zf);
    const float tg = tanh_fast(zg), so = sigm(zo);
    const float cn = sf * c + si * tg;
    const float hn = so * tanh_fast(cn);
    if (act) { c = cn; h = hn; }
}

// ---------------- k_prep --------------------------------------------------
// blocks 0..255: per-row active scan -> idxbuf, wlist (tail zero), nactG
// blocks 256..265: XW1[w][512] f32 (one word id per block)
// blocks 266..361: weight A-frags. A[m][k]: lane l holds m=l&15, k=8*(l>>4)+j.
//   frag r = w*16+g*4+kt: value = W[32kt+8lq+j][128g+16w+lm]
__global__ __launch_bounds__(256) void k_prep(
    const int* __restrict__ char_ids, const int* __restrict__ word_ids,
    const float* __restrict__ emb_char, const float* __restrict__ emb_word,
    const float* __restrict__ Wwc, const float* __restrict__ bwc,
    const float* __restrict__ l1_Wx, const float* __restrict__ l1_b,
    const float* __restrict__ l1_Wh, const float* __restrict__ l2_Wx,
    const float* __restrict__ l2_Wh,
    float* __restrict__ XW1, unsigned short* __restrict__ idxbuf,
    unsigned short* __restrict__ wlist, int* __restrict__ nactG,
    uint4* __restrict__ BW1, uint4* __restrict__ BWX, uint4* __restrict__ BWH)
{
    const int T = threadIdx.x;
    if (blockIdx.x < 256) {
        // ---- row scan ----
        __shared__ int charL[512];
        __shared__ int wordL[512];
        __shared__ short actT[512];
        __shared__ int ccnt[8];
        const int b = blockIdx.x;
        const int lane = T & 63;
        const int wv = T >> 6;
        charL[T] = char_ids[b * 512 + T];
        charL[256 + T] = char_ids[b * 512 + 256 + T];
        wordL[T] = word_ids[b * 512 + T];
        wordL[256 + T] = word_ids[b * 512 + 256 + T];
        __syncthreads();
        const bool a0 = (charL[T] == 0);
        const bool a1 = (charL[256 + T] == 0);
        const unsigned long long m0 = __ballot(a0);
        const unsigned long long m1 = __ballot(a1);
        if (lane == 0) { ccnt[wv] = (int)__popcll(m0); ccnt[4 + wv] = (int)__popcll(m1); }
        __syncthreads();
        int base0 = 0, base4 = 0, tot = 0;
        for (int i = 0; i < 8; ++i) {
            const int c = ccnt[i];
            if (i < wv) base0 += c;
            if (i < 4 + wv) base4 += c;
            tot += c;
        }
        const unsigned long long below = (1ull << lane) - 1ull;
        const unsigned long long upto  = (2ull << lane) - 1ull;
        if (a0) actT[base0 + (int)__popcll(m0 & below)] = (short)T;
        if (a1) actT[base4 + (int)__popcll(m1 & below)] = (short)(256 + T);
        {
            int c0 = base0 + (int)__popcll(m0 & upto);
            int c1 = base4 + (int)__popcll(m1 & upto);
            idxbuf[b * 512 + T] = (unsigned short)(c0 < SLOTCAP - 1 ? c0 : SLOTCAP - 1);
            idxbuf[b * 512 + 256 + T] = (unsigned short)(c1 < SLOTCAP - 1 ? c1 : SLOTCAP - 1);
        }
        __syncthreads();
        const int nclamp = (tot < SLOTCAP - 1) ? tot : SLOTCAP - 1;
        for (int a2 = T; a2 < SLOTCAP; a2 += 256)
            wlist[b * SLOTCAP + a2] =
                (a2 < nclamp) ? (unsigned short)wordL[actT[a2]] : (unsigned short)0;
        if (T == 0) nactG[b] = nclamp;
        return;
    }
    if (blockIdx.x < 266) {
        // ---- XW1 table, one word id per block ----
        __shared__ float xt[64];
        const int w = blockIdx.x - 256;
        if (T < 64) {
            float acc = emb_char[T] + bwc[T];   // emb_char row 0 (char_id==0)
            for (int m = 0; m < 32; ++m) acc += emb_word[w * 32 + m] * Wwc[m * 64 + T];
            xt[T] = acc;
        }
        __syncthreads();
        for (int col = T; col < 512; col += 256) {
            float acc = l1_b[col];
            for (int k = 0; k < 64; ++k) acc += xt[k] * l1_Wx[k * 512 + col];
            XW1[w * 512 + col] = acc;
        }
        return;
    }
    // ---- weight frag pack ----
    const int gid = (blockIdx.x - 266) * 256 + T;   // 0..24575
    const int fid = gid >> 6;                       // 0..383
    const int lane = gid & 63;
    const int m = fid >> 7;                         // 0=W1 1=WX 2=WH
    const int rsub = fid & 127;                     // = w*16+g*4+kt
    const int w = rsub >> 4, g = (rsub >> 2) & 3, kt = rsub & 3;
    const int lq = lane >> 4, lm = lane & 15;
    const int col = 128 * g + 16 * w + lm;
    const float* src = (m == 0) ? l1_Wh : (m == 1) ? l2_Wx : l2_Wh;
    uint4* dst = (m == 0) ? BW1 : (m == 1) ? BWX : BWH;
    Frag out;
    for (int j = 0; j < 8; ++j)
        out.h[j] = (_Float16)src[(32 * kt + 8 * lq + j) * 512 + col];
    dst[(size_t)rsub * 64 + lane] = out.u;
}

// ---------------- k_rec: fused 2-layer recurrence, 16 rows/block ------------
// amdgpu_waves_per_eu(2,2): pin occupancy at 2 waves/EU -> 256 unified
// regs/wave so the 48 weight frags (192 regs) stay resident. The scheduler's
// default 4-waves/EU target (128 regs) spills them to scratch (R4/R5:
// VGPR_Count=128, 343 us, ~8k cyc/step of L2 scratch reload).
__global__ __launch_bounds__(512)
__attribute__((amdgpu_waves_per_eu(2, 2))) void k_rec(
    const uint4* __restrict__ BW1, const uint4* __restrict__ BWX,
    const uint4* __restrict__ BWH, const float* __restrict__ XW1,
    const float* __restrict__ l2_b, const unsigned short* __restrict__ wlist,
    const int* __restrict__ nactG, float* __restrict__ hbuf)
{
    const int r = blockIdx.x;       // rows 16r..16r+15
    const int T = threadIdx.x;
    const int w = T >> 6, l = T & 63;
    const int lq = l >> 4, lm = l & 15;
    const int u0 = 16 * w + 4 * lq;         // unit base (lane owns u0..u0+3)
    const size_t rowbase = (size_t)(16 * r);

    __shared__ _Float16 hA[2][16][136];     // h1 double buffer, [row][k]
    __shared__ _Float16 hB[2][16][136];     // h2 double buffer
    __shared__ unsigned short wt[16][130];
    __shared__ int nactS[16];
    __shared__ int nmax_s;

    // resident weight A-frags: 48 x uint4 = 192 regs (MFMA operands)
    Frag wf1[16], wfx[16], wfh[16];
    {
        const uint4* p1 = BW1 + (size_t)(w * 16) * 64 + l;
        const uint4* px = BWX + (size_t)(w * 16) * 64 + l;
        const uint4* ph = BWH + (size_t)(w * 16) * 64 + l;
#pragma unroll
        for (int i = 0; i < 16; ++i) {
            wf1[i].u = p1[i * 64];
            wfx[i].u = px[i * 64];
            wfh[i].u = ph[i * 64];
        }
    }
    F4 b2[4];
#pragma unroll
    for (int g = 0; g < 4; ++g) b2[g].v = *(const float4*)&l2_b[128 * g + u0];

    for (int i = T; i < 2176; i += 512) {
        ((_Float16*)hA[0])[i] = (_Float16)0.f;
        ((_Float16*)hB[0])[i] = (_Float16)0.f;
    }
    for (int i = T; i < 2048; i += 512) {
        wt[i >> 7][i & 127] = wlist[(rowbase + (i >> 7)) * SLOTCAP + (i & 127)];
        hbuf[((rowbase + (i >> 7)) * SLOTCAP) * 128 + (i & 127)] = 0.f;  // slot 0
    }
    if (T < 16) nactS[T] = nactG[16 * r + T];
    __syncthreads();
    if (T == 0) {
        int mx = 0;
        for (int m = 0; m < 16; ++m) mx = nactS[m] > mx ? nactS[m] : mx;
        nmax_s = mx;
    }
    __syncthreads();
    const int nmax = nmax_s;
    const int nact_l = nactS[lm];

    float c1[4] = {0.f,0.f,0.f,0.f}, c2[4] = {0.f,0.f,0.f,0.f};
    float h1v[4] = {0.f,0.f,0.f,0.f}, h2v[4] = {0.f,0.f,0.f,0.f};

    for (int a = 0; a < nmax; ++a) {
        const int cur = a & 1, nxt = cur ^ 1;
        const bool act = (a < nact_l);
        const int wd = (int)wt[lm][a];
        // x-contribution (f32, L2-hot), issued early
        F4 xw[4];
#pragma unroll
        for (int g = 0; g < 4; ++g)
            xw[g].v = *(const float4*)&XW1[wd * 512 + 128 * g + u0];

        // ---- layer 1: z1^T tiles ----
        Frag hb1[4];
#pragma unroll
        for (int kt = 0; kt < 4; ++kt)
            hb1[kt].u = *(const uint4*)&hA[cur][lm][32 * kt + 8 * lq];
        floatx4 acc[4];
#pragma unroll
        for (int g = 0; g < 4; ++g) {
            floatx4 z = {0.f, 0.f, 0.f, 0.f};
#pragma unroll
            for (int kt = 0; kt < 4; ++kt)
                z = __builtin_amdgcn_mfma_f32_16x16x32_f16(wf1[g * 4 + kt].h, hb1[kt].h, z, 0, 0, 0);
            acc[g] = z;
        }
#pragma unroll
        for (int rr = 0; rr < 4; ++rr)
            lstm_gate(acc[0][rr] + xw[0].f[rr], acc[1][rr] + xw[1].f[rr],
                      acc[2][rr] + xw[2].f[rr], acc[3][rr] + xw[3].f[rr],
                      act, c1[rr], h1v[rr]);
        {
            H4 hh;
#pragma unroll
            for (int rr = 0; rr < 4; ++rr) hh.h[rr] = (_Float16)h1v[rr];
            *(short4*)&hA[nxt][lm][u0] = hh.s;
        }
        // h2 frags (from cur buffer; writes go to nxt) — safe pre-barrier
        Frag hb2[4];
#pragma unroll
        for (int kt = 0; kt < 4; ++kt)
            hb2[kt].u = *(const uint4*)&hB[cur][lm][32 * kt + 8 * lq];
        __syncthreads();   // h1-new visible

        // ---- layer 2 ----
        Frag hbn[4];
#pragma unroll
        for (int kt = 0; kt < 4; ++kt)
            hbn[kt].u = *(const uint4*)&hA[nxt][lm][32 * kt + 8 * lq];
#pragma unroll
        for (int g = 0; g < 4; ++g) {
            floatx4 z = {b2[g].f[0], b2[g].f[1], b2[g].f[2], b2[g].f[3]};
#pragma unroll
            for (int kt = 0; kt < 4; ++kt)
                z = __builtin_amdgcn_mfma_f32_16x16x32_f16(wfh[g * 4 + kt].h, hb2[kt].h, z, 0, 0, 0);
#pragma unroll
            for (int kt = 0; kt < 4; ++kt)
                z = __builtin_amdgcn_mfma_f32_16x16x32_f16(wfx[g * 4 + kt].h, hbn[kt].h, z, 0, 0, 0);
            acc[g] = z;
        }
#pragma unroll
        for (int rr = 0; rr < 4; ++rr)
            lstm_gate(acc[0][rr], acc[1][rr], acc[2][rr], acc[3][rr],
                      act, c2[rr], h2v[rr]);
        {
            H4 hh;
#pragma unroll
            for (int rr = 0; rr < 4; ++rr) hh.h[rr] = (_Float16)h2v[rr];
            *(short4*)&hB[nxt][lm][u0] = hh.s;
        }
        if (act) {
            float4 hv; hv.x = h2v[0]; hv.y = h2v[1]; hv.z = h2v[2]; hv.w = h2v[3];
            *(float4*)&hbuf[((rowbase + lm) * SLOTCAP + (a + 1)) * 128 + u0] = hv;
        }
        __syncthreads();   // h2-new visible / buffer rotate
    }
}

// ---------------- k_out: subject GEMV + per-slot LN/po/sub + scatter --------
__global__ __launch_bounds__(256) void k_out(
    const int* __restrict__ subject_ids,
    const unsigned short* __restrict__ idxbuf, const float* __restrict__ hbuf,
    const float* __restrict__ beta_W, const float* __restrict__ beta_b,
    const float* __restrict__ gamma_W, const float* __restrict__ gamma_b,
    const float* __restrict__ sub_W, const float* __restrict__ sub_b,
    const float* __restrict__ po_W, const float* __restrict__ po_b,
    float* __restrict__ out)
{
    const int b = blockIdx.x;
    const int T = threadIdx.x;   // 0..255
    __shared__ float A[20][132];          // A[o][c] = gm[c]*po_W[c*20+o]
    __shared__ float K1[20], K2[20];
    __shared__ float gm[128], bt[128];
    __shared__ float subj[256];
    __shared__ float urs[SLOTCAP][2];
    __shared__ float povals[SLOTCAP * 20];
    __shared__ float subv[SLOTCAP * 2];
    __shared__ unsigned short idxr[512];
    __shared__ float swl[256];

    idxr[T] = idxbuf[b * 512 + T];
    idxr[256 + T] = idxbuf[b * 512 + 256 + T];
    swl[T] = sub_W[T];
    {
        const int s0 = subject_ids[b * 2 + 0];
        const int s1 = subject_ids[b * 2 + 1];
        const int i0 = idxbuf[b * 512 + s0];
        const int i1 = idxbuf[b * 512 + s1];
        if (T < 128) subj[T] = hbuf[((size_t)b * SLOTCAP + i0) * 128 + T];
        else         subj[T] = hbuf[((size_t)b * SLOTCAP + i1) * 128 + (T - 128)];
    }
    __syncthreads();

    {   // beta (T<128) / gamma (T>=128) GEMV
        const int uu = T & 127;
        const float* Wm = (T < 128) ? beta_W : gamma_W;
        float acc = (T < 128) ? beta_b[uu] : gamma_b[uu];
        for (int c = 0; c < 256; ++c) acc += subj[c] * Wm[c * 128 + uu];
        if (T < 128) bt[uu] = acc; else gm[uu] = acc;
    }
    __syncthreads();

    for (int i = T; i < 2560; i += 256) {
        const int o = i >> 7, c = i & 127;
        A[o][c] = gm[c] * po_W[c * 20 + o];
    }
    if (T < 20) {
        float k1 = po_b[T], k2 = 0.f;
        for (int c = 0; c < 128; ++c) {
            const float pw = po_W[c * 20 + T];
            k1 += bt[c] * pw;
            k2 += gm[c] * pw;
        }
        K1[T] = k1; K2[T] = k2;
    }
    const int nslot = (int)idxr[511] + 1;
    const float sb0 = sub_b[0], sb1 = sub_b[1];
    for (int s = T; s < nslot; s += 256) {
        const float4* hp4 = (const float4*)(hbuf + ((size_t)b * SLOTCAP + s) * 128);
        float sum = 0.f, s2 = 0.f, sub0 = sb0, sub1 = sb1;
        for (int c4 = 0; c4 < 32; ++c4) {
            const float4 h = hp4[c4];
            sum += (h.x + h.y) + (h.z + h.w);
            s2  += h.x * h.x + h.y * h.y + h.z * h.z + h.w * h.w;
            const int c = 4 * c4;
            sub0 += h.x * swl[2 * c] + h.y * swl[2 * c + 2] + h.z * swl[2 * c + 4] + h.w * swl[2 * c + 6];
            sub1 += h.x * swl[2 * c + 1] + h.y * swl[2 * c + 3] + h.z * swl[2 * c + 5] + h.w * swl[2 * c + 7];
        }
        const float uu = sum * (1.f / 128.f);
        const float v = fmaxf(s2 * (1.f / 128.f) - uu * uu, 0.f);
        urs[s][0] = uu;
        urs[s][1] = 1.f / sqrtf(v + 1e-12f);
        subv[2 * s] = sub0; subv[2 * s + 1] = sub1;
    }
    __syncthreads();

    for (int i = T; i < nslot * 20; i += 256) {
        const int s = i / 20, o = i - 20 * s;
        const float uu = urs[s][0], rs = urs[s][1];
        const float4* hp4 = (const float4*)(hbuf + ((size_t)b * SLOTCAP + s) * 128);
        const float* Ao = &A[o][0];
        float acc = 0.f;
        for (int c4 = 0; c4 < 32; ++c4) {
            const float4 h = hp4[c4];
            const float4 aa = *(const float4*)&Ao[4 * c4];
            acc += h.x * aa.x + h.y * aa.y + h.z * aa.z + h.w * aa.w;
        }
        povals[i] = rs * acc - uu * rs * K2[o] + K1[o];
    }
    __syncthreads();

    for (int i = T; i < 2560; i += 256) {
        const int t = i / 5, j = i - 5 * t;
        const int sl = idxr[t];
        const float4 v = *(const float4*)&povals[sl * 20 + 4 * j];
        *(float4*)&out[262144 + ((size_t)(b * 512 + t)) * 20 + 4 * j] = v;
    }
    for (int i = T; i < 512; i += 256) {
        const int sl = idxr[i];
        float2 v; v.x = subv[2 * sl]; v.y = subv[2 * sl + 1];
        *(float2*)&out[((size_t)(b * 512 + i)) * 2] = v;
    }
}

extern "C" void kernel_launch(void* const* d_in, const int* in_sizes, int n_in,
                              void* d_out, int out_size, void* d_ws, size_t ws_size,
                              hipStream_t stream) {
    (void)in_sizes; (void)n_in; (void)out_size; (void)ws_size;
    const int*   char_ids    = (const int*)d_in[0];
    const int*   word_ids    = (const int*)d_in[1];
    const int*   subject_ids = (const int*)d_in[2];
    const float* emb_char    = (const float*)d_in[3];
    const float* emb_word    = (const float*)d_in[4];
    const float* Wwc         = (const float*)d_in[5];
    const float* bwc         = (const float*)d_in[6];
    const float* l1_Wx       = (const float*)d_in[7];
    const float* l1_Wh       = (const float*)d_in[8];
    const float* l1_b        = (const float*)d_in[9];
    const float* l2_Wx       = (const float*)d_in[10];
    const float* l2_Wh       = (const float*)d_in[11];
    const float* l2_b        = (const float*)d_in[12];
    const float* beta_W      = (const float*)d_in[13];
    const float* beta_b      = (const float*)d_in[14];
    const float* gamma_W     = (const float*)d_in[15];
    const float* gamma_b     = (const float*)d_in[16];
    const float* sub_W       = (const float*)d_in[17];
    const float* sub_b       = (const float*)d_in[18];
    const float* po_W        = (const float*)d_in[19];
    const float* po_b        = (const float*)d_in[20];
    float* out = (float*)d_out;

    char* ws = (char*)d_ws;
    float*          XW1    = (float*)(ws + 0);                // 20480 B (pad 32768)
    uint4*          BW1    = (uint4*)(ws + 32768);            // 131072 B
    uint4*          BWX    = (uint4*)(ws + 163840);           // 131072 B
    uint4*          BWH    = (uint4*)(ws + 294912);           // 131072 B
    unsigned short* idxbuf = (unsigned short*)(ws + 425984);  // 262144 B
    unsigned short* wlist  = (unsigned short*)(ws + 688128);  // 65536 B
    int*            nactG  = (int*)(ws + 753664);             // 1024 B
    float*          hbuf   = (float*)(ws + 786432);           // 16777216 B

    k_prep<<<dim3(362), dim3(256), 0, stream>>>(char_ids, word_ids, emb_char, emb_word,
                                                Wwc, bwc, l1_Wx, l1_b, l1_Wh, l2_Wx, l2_Wh,
                                                XW1, idxbuf, wlist, nactG, BW1, BWX, BWH);
    k_rec<<<dim3(16), dim3(512), 0, stream>>>(BW1, BWX, BWH, XW1, l2_b, wlist, nactG, hbuf);
    k_out<<<dim3(256), dim3(256), 0, stream>>>(subject_ids, idxbuf, hbuf,
                                               beta_W, beta_b, gamma_W, gamma_b,
                                               sub_W, sub_b, po_W, po_b, out);
}